// Round 5
// baseline (293.596 us; speedup 1.0000x reference)
//
#include <hip/hip_runtime.h>

#define NN 50000
#define TOPK 32
#define IN_C 128
#define OUT_C 64
#define NEG_SLOPE 0.2f
#define BN_EPS 1e-5f

// K1: MFMA, 16 nodes per block
#define K1_BLOCKS (NN / 16)         // 3125
// K2: 64-thread blocks, 1 wave = 8 nodes (8 lanes x 16B = full row)
#define K2_BLOCKS (NN / 8)          // 6250
#define SLOTS 20                    // 20 KB LDS -> 8 blocks/CU

// workspace layout (floats)
#define WS_XBF   0                       // bf16 x_lin: NN*64*2B
#define WS_AI    (NN * 32)
#define WS_AJ    (WS_AI + NN)
#define WS_SUMS  (WS_AJ + NN)            // 8 replicas x 128

typedef __bf16 bf16x8 __attribute__((ext_vector_type(8)));
typedef float f32x4 __attribute__((ext_vector_type(4)));
union BF8 { unsigned p[4]; bf16x8 v; };

__device__ inline float leaky(float a) { return a >= 0.f ? a : NEG_SLOPE * a; }
__device__ inline float bl(unsigned u) { return __uint_as_float(u << 16); }
__device__ inline float bh(unsigned u) { return __uint_as_float(u & 0xffff0000u); }

// fp32 -> bf16 via compiler cast (lowers to v_cvt_pk_bf16_f32, RNE)
__device__ inline unsigned pk2bf(float lo, float hi) {
    union { __bf16 b[2]; unsigned u; } cv;
    cv.b[0] = (__bf16)lo; cv.b[1] = (__bf16)hi;
    return cv.u;
}
__device__ inline unsigned short f2bf(float f) {
    union { __bf16 b; unsigned short u; } cv;
    cv.b = (__bf16)f;
    return cv.u;
}

// async global->LDS, 16 B per lane; LDS dest = base + lane*16 (HW rule)
__device__ inline void async16(const uint4* g, uint4* l) {
    __builtin_amdgcn_global_load_lds(
        (const __attribute__((address_space(1))) void*)(const void*)g,
        (__attribute__((address_space(3))) void*)(void*)l, 16, 0, 0);
}

// s_waitcnt immediates (gfx9 encoding: vm[3:0]|exp[6:4]|lgkm[11:8]|vm[5:4]@[15:14])
#define WAIT_VMCNT(n) __builtin_amdgcn_s_waitcnt(0x0F70 | (n))   // vmcnt(n), n<=15
#define WAIT_LGKM0()  __builtin_amdgcn_s_waitcnt(0xC07F)         // lgkmcnt(0)
#define SCHED_FENCE() __builtin_amdgcn_sched_barrier(0)

// K1: x_lin(bf16) = x @ lin_w^T via MFMA 16x16x32_bf16 + a_i/a_j epilogue.
__global__ __launch_bounds__(256) void k1_mfma(
    const float* __restrict__ x, const float* __restrict__ emb,
    const float* __restrict__ lin_w,
    const float* __restrict__ att_i, const float* __restrict__ att_j,
    const float* __restrict__ att_em_i, const float* __restrict__ att_em_j,
    unsigned short* __restrict__ x_bf, float* __restrict__ a_i,
    float* __restrict__ a_j, float* __restrict__ sums)
{
    __shared__ float redi[16][5], redj[16][5];
    __shared__ float eredi[16][17], eredj[16][17];
    const int tid = threadIdx.x;
    if (blockIdx.x == 0) {
#pragma unroll
        for (int i = 0; i < 4; ++i) sums[tid + i * 256] = 0.f;
    }

    const int lane = tid & 63;
    const int wv = tid >> 6;
    const int quad = lane >> 4;
    const int nn = lane & 15;
    const int base = blockIdx.x * 16;
    const int c = wv * 16 + nn;          // this lane's output channel

    BF8 bfr[4], afr[4];
    {
        const float* wr = lin_w + (size_t)c * IN_C + quad * 8;
        const float* xr = x + (size_t)(base + nn) * IN_C + quad * 8;
#pragma unroll
        for (int s = 0; s < 4; ++s) {
            const float4 wa = *(const float4*)(wr + s * 32);
            const float4 wb = *(const float4*)(wr + s * 32 + 4);
            const float4 xa = *(const float4*)(xr + s * 32);
            const float4 xb = *(const float4*)(xr + s * 32 + 4);
            bfr[s].p[0] = pk2bf(wa.x, wa.y);
            bfr[s].p[1] = pk2bf(wa.z, wa.w);
            bfr[s].p[2] = pk2bf(wb.x, wb.y);
            bfr[s].p[3] = pk2bf(wb.z, wb.w);
            afr[s].p[0] = pk2bf(xa.x, xa.y);
            afr[s].p[1] = pk2bf(xa.z, xa.w);
            afr[s].p[2] = pk2bf(xb.x, xb.y);
            afr[s].p[3] = pk2bf(xb.z, xb.w);
        }
    }

    f32x4 acc = {0.f, 0.f, 0.f, 0.f};
#pragma unroll
    for (int s = 0; s < 4; ++s)
        acc = __builtin_amdgcn_mfma_f32_16x16x32_bf16(afr[s].v, bfr[s].v, acc,
                                                      0, 0, 0);

    const float aic = att_i[c], ajc = att_j[c];
    float pi[4], pj[4];
#pragma unroll
    for (int r = 0; r < 4; ++r) {
        const int node = base + quad * 4 + r;
        x_bf[(size_t)node * OUT_C + c] = f2bf(acc[r]);
        pi[r] = acc[r] * aic;
        pj[r] = acc[r] * ajc;
    }
#pragma unroll
    for (int d = 1; d < 16; d <<= 1) {
#pragma unroll
        for (int r = 0; r < 4; ++r) {
            pi[r] += __shfl_xor(pi[r], d, 64);
            pj[r] += __shfl_xor(pj[r], d, 64);
        }
    }
    if (nn == 0) {
#pragma unroll
        for (int r = 0; r < 4; ++r) {
            redi[quad * 4 + r][wv] = pi[r];
            redj[quad * 4 + r][wv] = pj[r];
        }
    }
    {
        const int nl = tid >> 4, c4 = tid & 15;
        const float4 e4 = ((const float4*)emb)[(size_t)(base + nl) * 16 + c4];
        const float4 i4 = ((const float4*)att_em_i)[c4];
        const float4 j4 = ((const float4*)att_em_j)[c4];
        eredi[nl][c4] = e4.x * i4.x + e4.y * i4.y + e4.z * i4.z + e4.w * i4.w;
        eredj[nl][c4] = e4.x * j4.x + e4.y * j4.y + e4.z * j4.z + e4.w * j4.w;
    }
    __syncthreads();
    if (tid < 16) {
        float si = redi[tid][0] + redi[tid][1] + redi[tid][2] + redi[tid][3];
        float sj = redj[tid][0] + redj[tid][1] + redj[tid][2] + redj[tid][3];
#pragma unroll
        for (int r = 0; r < 16; ++r) { si += eredi[tid][r]; sj += eredj[tid][r]; }
        a_i[base + tid] = si;
        a_j[base + tid] = sj;
    }
}

// per-edge accumulate: row u (8 bf16 channels) * weight w into A[8]
__device__ inline void accr(float* A, const uint4 u, const float w) {
    A[0] = fmaf(w, bl(u.x), A[0]); A[1] = fmaf(w, bh(u.x), A[1]);
    A[2] = fmaf(w, bl(u.y), A[2]); A[3] = fmaf(w, bh(u.y), A[3]);
    A[4] = fmaf(w, bl(u.z), A[4]); A[5] = fmaf(w, bh(u.z), A[5]);
    A[6] = fmaf(w, bl(u.w), A[6]); A[7] = fmaf(w, bh(u.w), A[7]);
}

// K2 v6: round-0 proven core — EVERY row gathered via global_load_lds (zero
// VGPR-dest row buffers; round-0's "all in flight at once" engine) — plus
// occupancy via SLOT REUSE: 20 slots (20 KB -> 8 blocks/CU, 2 waves/SIMD vs
// round-0's 1). Consume e0..7 -> refill slots 0..7 with e20..27; consume
// e8..12 -> refill slots 8..12 with e28..31+self; counted vmcnt(5)/vmcnt(0)
// gates the reused slots. R2-R4 post-mortem: 12-13 uint4 register rows
// (48+ VGPR) partially spilled at the drain (WRITE 3x output in all three);
// all-LDS staging removes the pressure entirely.
__global__ __launch_bounds__(64) void k2_attn(
    const int* __restrict__ src, const uint4* __restrict__ x_bf4,
    const float* __restrict__ a_j, const float* __restrict__ a_i,
    const float* __restrict__ bias, float* __restrict__ out,
    float* __restrict__ sums)
{
    __shared__ uint4 stage[SLOTS * 64];  // 20 KB

    const int tid = threadIdx.x;         // == lane (64-thread block)
    const int g = tid >> 3;              // node within group of 8
    const int q = tid & 7;               // row slice
    const int gb = tid & 56;             // g*8 = first lane of this group
    const int t = blockIdx.x * 8 + g;

    const int4* sp4 = (const int4*)(src + (size_t)t * TOPK);
    const int4 i0 = sp4[0], i1 = sp4[1], i2 = sp4[2], i3 = sp4[3], i4 = sp4[4];
    const int4 sq = sp4[q];              // this lane's softmax partition

    // logit inputs issued BEFORE the staged gathers: softmax then waits only
    // on these (counted vmcnt), overlapping the 20 in-flight row-gathers.
    const float ai_t = a_i[t];
    const float aj0 = a_j[sq.x], aj1 = a_j[sq.y];
    const float aj2 = a_j[sq.z], aj3 = a_j[sq.w];
    const float ajs = a_j[t];

    // stage edges 0..19 -> slots 0..19
#define STG(iv, s0) do {                                                    \
        async16(x_bf4 + ((size_t)(iv).x * 8 + q), &stage[((s0) + 0) * 64]); \
        async16(x_bf4 + ((size_t)(iv).y * 8 + q), &stage[((s0) + 1) * 64]); \
        async16(x_bf4 + ((size_t)(iv).z * 8 + q), &stage[((s0) + 2) * 64]); \
        async16(x_bf4 + ((size_t)(iv).w * 8 + q), &stage[((s0) + 3) * 64]); \
    } while (0)
    STG(i0, 0); STG(i1, 4); STG(i2, 8); STG(i3, 12); STG(i4, 16);

    // softmax over 33 edges: lane q owns edges q*4..q*4+3
    float l0 = leaky(ai_t + aj0);
    float l1 = leaky(ai_t + aj1);
    float l2 = leaky(ai_t + aj2);
    float l3 = leaky(ai_t + aj3);
    const float ls = leaky(ai_t + ajs);
    float mx = fmaxf(fmaxf(l0, l1), fmaxf(l2, l3));
#pragma unroll
    for (int d = 1; d < 8; d <<= 1) mx = fmaxf(mx, __shfl_xor(mx, d, 64));
    mx = fmaxf(mx, ls);
    const float e0 = __expf(l0 - mx), e1 = __expf(l1 - mx);
    const float e2 = __expf(l2 - mx), e3 = __expf(l3 - mx);
    const float es = __expf(ls - mx);
    float den = (e0 + e1) + (e2 + e3);
#pragma unroll
    for (int d = 1; d < 8; d <<= 1) den += __shfl_xor(den, d, 64);
    den += es + 1e-16f;
    const float inv = 1.f / den;
    const float w0 = e0 * inv, w1 = e1 * inv, w2 = e2 * inv, w3 = e3 * inv;
    const float wself = es * inv;        // group-uniform

    WAIT_VMCNT(0);                       // slots 0..19 resident
    SCHED_FENCE();

    // refill indices, reloaded from L1 (not held live across the kernel)
    const int4 i5 = sp4[5], i6 = sp4[6], i7 = sp4[7];

    float A[8];
#pragma unroll
    for (int j = 0; j < 8; ++j) A[j] = 0.f;

    // edge e = 4b+k: weight w{k} lives in lane gb+b
#define EDGE(slot, wsrc, b) do {                                            \
        const float w_ = __shfl((wsrc), gb + (b), 64);                      \
        accr(A, stage[(slot) * 64 + tid], w_);                              \
    } while (0)

    // e0..7 (slots 0..7)
    EDGE(0, w0, 0); EDGE(1, w1, 0); EDGE(2, w2, 0); EDGE(3, w3, 0);
    EDGE(4, w0, 1); EDGE(5, w1, 1); EDGE(6, w2, 1); EDGE(7, w3, 1);

    // WAR guard, then refill A: e20..27 -> slots 0..7
    WAIT_LGKM0();
    SCHED_FENCE();
    STG(i5, 0); STG(i6, 4);

    // e8..12 (slots 8..12)
    EDGE(8, w0, 2); EDGE(9, w1, 2); EDGE(10, w2, 2); EDGE(11, w3, 2);
    EDGE(12, w0, 3);

    // WAR guard, then refill B: e28..31 -> slots 8..11, self -> slot 12
    WAIT_LGKM0();
    SCHED_FENCE();
    STG(i7, 8);
    async16(x_bf4 + ((size_t)t * 8 + q), &stage[12 * 64]);

    // e13..19 (slots 13..19)
    EDGE(13, w1, 3); EDGE(14, w2, 3); EDGE(15, w3, 3);
    EDGE(16, w0, 4); EDGE(17, w1, 4); EDGE(18, w2, 4); EDGE(19, w3, 4);

    WAIT_VMCNT(5);                       // refill A (oldest 8) retired
    SCHED_FENCE();
    // e20..27 (slots 0..7)
    EDGE(0, w0, 5); EDGE(1, w1, 5); EDGE(2, w2, 5); EDGE(3, w3, 5);
    EDGE(4, w0, 6); EDGE(5, w1, 6); EDGE(6, w2, 6); EDGE(7, w3, 6);

    WAIT_VMCNT(0);                       // refill B retired
    SCHED_FENCE();
    // e28..31 (slots 8..11) + self (slot 12)
    EDGE(8, w0, 7); EDGE(9, w1, 7); EDGE(10, w2, 7); EDGE(11, w3, 7);
    accr(A, stage[12 * 64 + tid], wself);
#undef EDGE
#undef STG

    const float4 b0 = ((const float4*)bias)[q * 2];
    const float4 b1 = ((const float4*)bias)[q * 2 + 1];
    float v[8];
    v[0] = A[0] + b0.x; v[1] = A[1] + b0.y; v[2] = A[2] + b0.z; v[3] = A[3] + b0.w;
    v[4] = A[4] + b1.x; v[5] = A[5] + b1.y; v[6] = A[6] + b1.z; v[7] = A[7] + b1.w;
    float4* o4 = (float4*)(out + (size_t)t * OUT_C + q * 8);
    o4[0] = make_float4(v[0], v[1], v[2], v[3]);
    o4[1] = make_float4(v[4], v[5], v[6], v[7]);

    // BN partials: reduce over the wave's 8 nodes (g axis = lane bits 3..5)
    float s1[8], s2[8];
#pragma unroll
    for (int j = 0; j < 8; ++j) { s1[j] = v[j]; s2[j] = v[j] * v[j]; }
#pragma unroll
    for (int d = 8; d < 64; d <<= 1) {
#pragma unroll
        for (int j = 0; j < 8; ++j) {
            s1[j] += __shfl_xor(s1[j], d, 64);
            s2[j] += __shfl_xor(s2[j], d, 64);
        }
    }
    if (tid < 8) {                       // lane q=tid holds channels tid*8+j
        float* rep = sums + (blockIdx.x & 7) * 128;
#pragma unroll
        for (int j = 0; j < 8; ++j) {
            atomicAdd(&rep[tid * 8 + j], s1[j]);
            atomicAdd(&rep[64 + tid * 8 + j], s2[j]);
        }
    }
}

// K4: BN stats from the 8 sum replicas (redundant per block), apply + ReLU.
__global__ __launch_bounds__(256) void k4_bn(
    float* __restrict__ out, const float* __restrict__ sums,
    const float* __restrict__ gamma, const float* __restrict__ beta)
{
    __shared__ float s_sc[64], s_sh[64];
    const int tid = threadIdx.x;
    if (tid < 64) {
        float s1 = 0.f, s2 = 0.f;
#pragma unroll
        for (int r = 0; r < 8; ++r) {
            s1 += sums[r * 128 + tid];
            s2 += sums[r * 128 + 64 + tid];
        }
        const float mu = s1 / (float)NN;
        const float ex2 = s2 / (float)NN;
        const float var = fmaxf(ex2 - mu * mu, 0.f);
        const float sc = gamma[tid] / sqrtf(var + BN_EPS);
        s_sc[tid] = sc;
        s_sh[tid] = beta[tid] - mu * sc;
    }
    __syncthreads();
    const int total = NN * OUT_C / 4;
    float4* p = (float4*)out;
    for (int idx = blockIdx.x * 256 + tid; idx < total; idx += gridDim.x * 256) {
        float4 v = p[idx];
        const int c0 = (idx & 15) * 4;
        v.x = fmaxf(fmaf(v.x, s_sc[c0 + 0], s_sh[c0 + 0]), 0.f);
        v.y = fmaxf(fmaf(v.y, s_sc[c0 + 1], s_sh[c0 + 1]), 0.f);
        v.z = fmaxf(fmaf(v.z, s_sc[c0 + 2], s_sh[c0 + 2]), 0.f);
        v.w = fmaxf(fmaf(v.w, s_sc[c0 + 3], s_sh[c0 + 3]), 0.f);
        p[idx] = v;
    }
}

extern "C" void kernel_launch(void* const* d_in, const int* in_sizes, int n_in,
                              void* d_out, int out_size, void* d_ws, size_t ws_size,
                              hipStream_t stream) {
    const float* x        = (const float*)d_in[0];
    const float* emb      = (const float*)d_in[1];
    const int*   edge     = (const int*)d_in[2];   // row 0 = src
    const float* lin_w    = (const float*)d_in[3];
    const float* att_i    = (const float*)d_in[4];
    const float* att_j    = (const float*)d_in[5];
    const float* att_em_i = (const float*)d_in[6];
    const float* att_em_j = (const float*)d_in[7];
    const float* bias     = (const float*)d_in[8];
    const float* gamma    = (const float*)d_in[9];
    const float* beta     = (const float*)d_in[10];

    float* ws    = (float*)d_ws;
    unsigned short* x_bf = (unsigned short*)(ws + WS_XBF);
    float* a_i   = ws + WS_AI;
    float* a_j   = ws + WS_AJ;
    float* sums  = ws + WS_SUMS;
    float* out   = (float*)d_out;

    k1_mfma<<<K1_BLOCKS, 256, 0, stream>>>(x, emb, lin_w, att_i, att_j,
                                           att_em_i, att_em_j, x_bf, a_i, a_j, sums);
    k2_attn<<<K2_BLOCKS, 64, 0, stream>>>(edge, (const uint4*)x_bf, a_j, a_i,
                                          bias, out, sums);
    k4_bn<<<1024, 256, 0, stream>>>(out, sums, gamma, beta);
}

// Round 6
// 164.145 us; speedup vs baseline: 1.7886x; 1.7886x over previous
//
#include <hip/hip_runtime.h>

#define NN 50000
#define TOPK 32
#define IN_C 128
#define OUT_C 64
#define NEG_SLOPE 0.2f
#define BN_EPS 1e-5f

// K1: MFMA, 16 nodes per block
#define K1_BLOCKS (NN / 16)         // 3125
// K2: 64-thread blocks, 1 wave = 8 nodes (8 lanes x 16B = full row)
#define K2_BLOCKS (NN / 8)          // 6250

// workspace layout (floats)
#define WS_XBF   0                       // bf16 x_lin: NN*64*2B
#define WS_AI    (NN * 32)
#define WS_AJ    (WS_AI + NN)
#define WS_SUMS  (WS_AJ + NN)            // 8 replicas x 128

typedef __bf16 bf16x8 __attribute__((ext_vector_type(8)));
typedef float f32x4 __attribute__((ext_vector_type(4)));
union BF8 { unsigned p[4]; bf16x8 v; };

__device__ inline float leaky(float a) { return a >= 0.f ? a : NEG_SLOPE * a; }
__device__ inline float bl(unsigned u) { return __uint_as_float(u << 16); }
__device__ inline float bh(unsigned u) { return __uint_as_float(u & 0xffff0000u); }

// fp32 -> bf16 via compiler cast (lowers to v_cvt_pk_bf16_f32, RNE — same
// rounding as the manual sequence; kept from R1, neutral across R1-R5)
__device__ inline unsigned pk2bf(float lo, float hi) {
    union { __bf16 b[2]; unsigned u; } cv;
    cv.b[0] = (__bf16)lo; cv.b[1] = (__bf16)hi;
    return cv.u;
}
__device__ inline unsigned short f2bf(float f) {
    union { __bf16 b; unsigned short u; } cv;
    cv.b = (__bf16)f;
    return cv.u;
}

// async global->LDS, 16 B per lane; LDS dest = base + lane*16 (HW rule)
__device__ inline void async16(const uint4* g, uint4* l) {
    __builtin_amdgcn_global_load_lds(
        (const __attribute__((address_space(1))) void*)(const void*)g,
        (__attribute__((address_space(3))) void*)(void*)l, 16, 0, 0);
}

// K1: x_lin(bf16) = x @ lin_w^T via MFMA 16x16x32_bf16 + a_i/a_j epilogue.
__global__ __launch_bounds__(256) void k1_mfma(
    const float* __restrict__ x, const float* __restrict__ emb,
    const float* __restrict__ lin_w,
    const float* __restrict__ att_i, const float* __restrict__ att_j,
    const float* __restrict__ att_em_i, const float* __restrict__ att_em_j,
    unsigned short* __restrict__ x_bf, float* __restrict__ a_i,
    float* __restrict__ a_j, float* __restrict__ sums)
{
    __shared__ float redi[16][5], redj[16][5];
    __shared__ float eredi[16][17], eredj[16][17];
    const int tid = threadIdx.x;
    if (blockIdx.x == 0) {
#pragma unroll
        for (int i = 0; i < 4; ++i) sums[tid + i * 256] = 0.f;
    }

    const int lane = tid & 63;
    const int wv = tid >> 6;
    const int quad = lane >> 4;
    const int nn = lane & 15;
    const int base = blockIdx.x * 16;
    const int c = wv * 16 + nn;          // this lane's output channel

    BF8 bfr[4], afr[4];
    {
        const float* wr = lin_w + (size_t)c * IN_C + quad * 8;
        const float* xr = x + (size_t)(base + nn) * IN_C + quad * 8;
#pragma unroll
        for (int s = 0; s < 4; ++s) {
            const float4 wa = *(const float4*)(wr + s * 32);
            const float4 wb = *(const float4*)(wr + s * 32 + 4);
            const float4 xa = *(const float4*)(xr + s * 32);
            const float4 xb = *(const float4*)(xr + s * 32 + 4);
            bfr[s].p[0] = pk2bf(wa.x, wa.y);
            bfr[s].p[1] = pk2bf(wa.z, wa.w);
            bfr[s].p[2] = pk2bf(wb.x, wb.y);
            bfr[s].p[3] = pk2bf(wb.z, wb.w);
            afr[s].p[0] = pk2bf(xa.x, xa.y);
            afr[s].p[1] = pk2bf(xa.z, xa.w);
            afr[s].p[2] = pk2bf(xb.x, xb.y);
            afr[s].p[3] = pk2bf(xb.z, xb.w);
        }
    }

    f32x4 acc = {0.f, 0.f, 0.f, 0.f};
#pragma unroll
    for (int s = 0; s < 4; ++s)
        acc = __builtin_amdgcn_mfma_f32_16x16x32_bf16(afr[s].v, bfr[s].v, acc,
                                                      0, 0, 0);

    const float aic = att_i[c], ajc = att_j[c];
    float pi[4], pj[4];
#pragma unroll
    for (int r = 0; r < 4; ++r) {
        const int node = base + quad * 4 + r;
        x_bf[(size_t)node * OUT_C + c] = f2bf(acc[r]);
        pi[r] = acc[r] * aic;
        pj[r] = acc[r] * ajc;
    }
#pragma unroll
    for (int d = 1; d < 16; d <<= 1) {
#pragma unroll
        for (int r = 0; r < 4; ++r) {
            pi[r] += __shfl_xor(pi[r], d, 64);
            pj[r] += __shfl_xor(pj[r], d, 64);
        }
    }
    if (nn == 0) {
#pragma unroll
        for (int r = 0; r < 4; ++r) {
            redi[quad * 4 + r][wv] = pi[r];
            redj[quad * 4 + r][wv] = pj[r];
        }
    }
    {
        const int nl = tid >> 4, c4 = tid & 15;
        const float4 e4 = ((const float4*)emb)[(size_t)(base + nl) * 16 + c4];
        const float4 i4 = ((const float4*)att_em_i)[c4];
        const float4 j4 = ((const float4*)att_em_j)[c4];
        eredi[nl][c4] = e4.x * i4.x + e4.y * i4.y + e4.z * i4.z + e4.w * i4.w;
        eredj[nl][c4] = e4.x * j4.x + e4.y * j4.y + e4.z * j4.z + e4.w * j4.w;
    }
    __syncthreads();
    if (tid < 16) {
        float si = redi[tid][0] + redi[tid][1] + redi[tid][2] + redi[tid][3];
        float sj = redj[tid][0] + redj[tid][1] + redj[tid][2] + redj[tid][3];
#pragma unroll
        for (int r = 0; r < 16; ++r) { si += eredi[tid][r]; sj += eredj[tid][r]; }
        a_i[base + tid] = si;
        a_j[base + tid] = sj;
    }
}

// K2: EXACT round-0 kernel (verified ~40 us / 161.7 total). One wave per
// block, 8 nodes per wave (lane = g*8+q: node g, 16B row slice q). All 33
// row-gathers issued as global_load_lds (no VGPR dest -> all in flight at
// once), one vmcnt(0) drain, then consume from LDS. Softmax 8-lane
// partitioned; weights cross lanes via small LDS buffer. BN partials
// atomicAdd to 1-of-8 sum replicas.
// R2-R5 post-mortem: every deviation (shfl exchanges, fewer slots, slot
// reuse, register rows) landed at 165-172 us; round-0 structure sustained
// 3.25 TB/s gather stream vs 340 GB/s for all variants. Reverted exactly.
__global__ __launch_bounds__(64) void k2_attn(
    const int* __restrict__ src, const uint4* __restrict__ x_bf4,
    const float* __restrict__ a_j, const float* __restrict__ a_i,
    const float* __restrict__ bias, float* __restrict__ out,
    float* __restrict__ sums)
{
    __shared__ uint4 stage[33 * 64];     // 33 KB staged rows
    __shared__ float wbuf[8][36];        // per-node 33 weights (+pad)
    __shared__ float sb1[64][9], sb2[64][9];

    const int tid = threadIdx.x;         // == lane (64-thread block)
    const int g = tid >> 3;              // node within group of 8
    const int q = tid & 7;               // row slice
    const int t = blockIdx.x * 8 + g;

    // all 32 src indices of this lane's node (broadcast across its 8 lanes)
    const int4* sp4 = (const int4*)(src + (size_t)t * TOPK);
    int4 s4[8];
#pragma unroll
    for (int i = 0; i < 8; ++i) s4[i] = sp4[i];
    const int4 sq = sp4[q];              // this lane's softmax partition

    // issue all 33 gathers: edge e of each node -> stage[e*64 + lane]
#pragma unroll
    for (int i = 0; i < 8; ++i) {
        async16(x_bf4 + ((size_t)s4[i].x * 8 + q), &stage[(i * 4 + 0) * 64]);
        async16(x_bf4 + ((size_t)s4[i].y * 8 + q), &stage[(i * 4 + 1) * 64]);
        async16(x_bf4 + ((size_t)s4[i].z * 8 + q), &stage[(i * 4 + 2) * 64]);
        async16(x_bf4 + ((size_t)s4[i].w * 8 + q), &stage[(i * 4 + 3) * 64]);
    }
    async16(x_bf4 + ((size_t)t * 8 + q), &stage[32 * 64]);   // self row

    // softmax over 33 edges: lane q owns edges q*4..q*4+3
    const float ai_t = a_i[t];
    float l0 = leaky(ai_t + a_j[sq.x]);
    float l1 = leaky(ai_t + a_j[sq.y]);
    float l2 = leaky(ai_t + a_j[sq.z]);
    float l3 = leaky(ai_t + a_j[sq.w]);
    const float ls = leaky(ai_t + a_j[t]);
    float mx = fmaxf(fmaxf(l0, l1), fmaxf(l2, l3));
#pragma unroll
    for (int d = 1; d < 8; d <<= 1) mx = fmaxf(mx, __shfl_xor(mx, d, 64));
    mx = fmaxf(mx, ls);
    const float e0 = __expf(l0 - mx), e1 = __expf(l1 - mx);
    const float e2 = __expf(l2 - mx), e3 = __expf(l3 - mx);
    const float es = __expf(ls - mx);
    float den = (e0 + e1) + (e2 + e3);
#pragma unroll
    for (int d = 1; d < 8; d <<= 1) den += __shfl_xor(den, d, 64);
    den += es + 1e-16f;
    const float inv = 1.f / den;

    ((float4*)&wbuf[g][q * 4])[0] =
        make_float4(e0 * inv, e1 * inv, e2 * inv, e3 * inv);
    if (q == 0) wbuf[g][32] = es * inv;
    __syncthreads();                      // single wave: cheap

    float4 w4[8];
#pragma unroll
    for (int i = 0; i < 8; ++i) w4[i] = ((const float4*)wbuf[g])[i];
    const float wself = wbuf[g][32];

    __builtin_amdgcn_s_waitcnt(0x0F70);   // vmcnt(0): all staged rows ready
    __syncthreads();

    float A[8];
#pragma unroll
    for (int j = 0; j < 8; ++j) A[j] = 0.f;
#pragma unroll
    for (int e = 0; e < 33; ++e) {
        const uint4 u = stage[e * 64 + tid];
        const float w = (e < 32) ? ((const float*)&w4[e >> 2])[e & 3] : wself;
        A[0] = fmaf(w, bl(u.x), A[0]); A[1] = fmaf(w, bh(u.x), A[1]);
        A[2] = fmaf(w, bl(u.y), A[2]); A[3] = fmaf(w, bh(u.y), A[3]);
        A[4] = fmaf(w, bl(u.z), A[4]); A[5] = fmaf(w, bh(u.z), A[5]);
        A[6] = fmaf(w, bl(u.w), A[6]); A[7] = fmaf(w, bh(u.w), A[7]);
    }
    const float4 b0 = ((const float4*)bias)[q * 2];
    const float4 b1 = ((const float4*)bias)[q * 2 + 1];
    float v[8];
    v[0] = A[0] + b0.x; v[1] = A[1] + b0.y; v[2] = A[2] + b0.z; v[3] = A[3] + b0.w;
    v[4] = A[4] + b1.x; v[5] = A[5] + b1.y; v[6] = A[6] + b1.z; v[7] = A[7] + b1.w;
    float4* o4 = (float4*)(out + (size_t)t * OUT_C + q * 8);
    o4[0] = make_float4(v[0], v[1], v[2], v[3]);
    o4[1] = make_float4(v[4], v[5], v[6], v[7]);

    // BN partials: channel c = q*8+j, reduce over the 8 nodes (col g)
#pragma unroll
    for (int j = 0; j < 8; ++j) {
        sb1[q * 8 + j][g] = v[j];
        sb2[q * 8 + j][g] = v[j] * v[j];
    }
    __syncthreads();
    {
        float t1 = 0.f, t2 = 0.f;
#pragma unroll
        for (int r = 0; r < 8; ++r) { t1 += sb1[tid][r]; t2 += sb2[tid][r]; }
        float* rep = sums + (blockIdx.x & 7) * 128;
        atomicAdd(&rep[tid], t1);
        atomicAdd(&rep[64 + tid], t2);
    }
}

// K4: BN stats from the 8 sum replicas (redundant per block), apply + ReLU.
__global__ __launch_bounds__(256) void k4_bn(
    float* __restrict__ out, const float* __restrict__ sums,
    const float* __restrict__ gamma, const float* __restrict__ beta)
{
    __shared__ float s_sc[64], s_sh[64];
    const int tid = threadIdx.x;
    if (tid < 64) {
        float s1 = 0.f, s2 = 0.f;
#pragma unroll
        for (int r = 0; r < 8; ++r) {
            s1 += sums[r * 128 + tid];
            s2 += sums[r * 128 + 64 + tid];
        }
        const float mu = s1 / (float)NN;
        const float ex2 = s2 / (float)NN;
        const float var = fmaxf(ex2 - mu * mu, 0.f);
        const float sc = gamma[tid] / sqrtf(var + BN_EPS);
        s_sc[tid] = sc;
        s_sh[tid] = beta[tid] - mu * sc;
    }
    __syncthreads();
    const int total = NN * OUT_C / 4;
    float4* p = (float4*)out;
    for (int idx = blockIdx.x * 256 + tid; idx < total; idx += gridDim.x * 256) {
        float4 v = p[idx];
        const int c0 = (idx & 15) * 4;
        v.x = fmaxf(fmaf(v.x, s_sc[c0 + 0], s_sh[c0 + 0]), 0.f);
        v.y = fmaxf(fmaf(v.y, s_sc[c0 + 1], s_sh[c0 + 1]), 0.f);
        v.z = fmaxf(fmaf(v.z, s_sc[c0 + 2], s_sh[c0 + 2]), 0.f);
        v.w = fmaxf(fmaf(v.w, s_sc[c0 + 3], s_sh[c0 + 3]), 0.f);
        p[idx] = v;
    }
}

extern "C" void kernel_launch(void* const* d_in, const int* in_sizes, int n_in,
                              void* d_out, int out_size, void* d_ws, size_t ws_size,
                              hipStream_t stream) {
    const float* x        = (const float*)d_in[0];
    const float* emb      = (const float*)d_in[1];
    const int*   edge     = (const int*)d_in[2];   // row 0 = src
    const float* lin_w    = (const float*)d_in[3];
    const float* att_i    = (const float*)d_in[4];
    const float* att_j    = (const float*)d_in[5];
    const float* att_em_i = (const float*)d_in[6];
    const float* att_em_j = (const float*)d_in[7];
    const float* bias     = (const float*)d_in[8];
    const float* gamma    = (const float*)d_in[9];
    const float* beta     = (const float*)d_in[10];

    float* ws    = (float*)d_ws;
    unsigned short* x_bf = (unsigned short*)(ws + WS_XBF);
    float* a_i   = ws + WS_AI;
    float* a_j   = ws + WS_AJ;
    float* sums  = ws + WS_SUMS;
    float* out   = (float*)d_out;

    k1_mfma<<<K1_BLOCKS, 256, 0, stream>>>(x, emb, lin_w, att_i, att_j,
                                           att_em_i, att_em_j, x_bf, a_i, a_j, sums);
    k2_attn<<<K2_BLOCKS, 64, 0, stream>>>(edge, (const uint4*)x_bf, a_j, a_i,
                                          bias, out, sums);
    k4_bn<<<1024, 256, 0, stream>>>(out, sums, gamma, beta);
}